// Round 5
// baseline (602.507 us; speedup 1.0000x reference)
//
#include <hip/hip_runtime.h>
#include <hip/hip_bf16.h>

#define D_MODEL 1024
#define N_HEAD  16
#define HD      64
#define T_SEQ   2048
#define B_SZ    4
#define M_ROWS  (B_SZ * T_SEQ)   // 8192

typedef __bf16 bf16;
typedef __bf16 bf16x4 __attribute__((ext_vector_type(4)));
typedef __bf16 bf16x8 __attribute__((ext_vector_type(8)));
typedef float  floatx4 __attribute__((ext_vector_type(4)));

__device__ __forceinline__ floatx4 fzero4() {
    floatx4 z = {0.f, 0.f, 0.f, 0.f};
    return z;
}

// async global->LDS, 16B/lane. LDS dest = wave-uniform base + lane*16.
__device__ __forceinline__ void async_ld16(const void* g, void* l) {
    __builtin_amdgcn_global_load_lds(
        (const __attribute__((address_space(1))) void*)g,
        (__attribute__((address_space(3))) void*)l,
        16, 0, 0);
}

struct CvtArgs {
    const float* s[7];
    bf16* d[7];
    int n[7];
};

// fused fp32 -> bf16 convert: 7 segments selected by blockIdx.y
__global__ __launch_bounds__(256) void cvt7_kernel(CvtArgs a)
{
    const float* src = a.s[blockIdx.y];
    bf16* dst = a.d[blockIdx.y];
    int n8 = a.n[blockIdx.y];
    int i = blockIdx.x * blockDim.x + threadIdx.x;
    int stride = gridDim.x * blockDim.x;
    for (; i < n8; i += stride) {
        float4 x = ((const float4*)src)[2 * i];
        float4 y = ((const float4*)src)[2 * i + 1];
        bf16x8 o;
        o[0] = (bf16)x.x; o[1] = (bf16)x.y; o[2] = (bf16)x.z; o[3] = (bf16)x.w;
        o[4] = (bf16)y.x; o[5] = (bf16)y.y; o[6] = (bf16)y.z; o[7] = (bf16)y.w;
        ((bf16x8*)dst)[i] = o;
    }
}

// C[8192,1024] = (A(bf16) @ W^T(bf16 [N,K]) + bias) * scl.
// LDS tiles XOR-swizzled: row r's 16B chunk c stored at pos c^(r&7).
// OMODE: 0 = bf16 head-split [B,H,T,64]; 1 = bf16 [B,H,64,T] (V); 2 = fp32 [M,N]
template <int OMODE>
__global__ __launch_bounds__(256) void gemm_bf16(
    const bf16* __restrict__ A0, const bf16* __restrict__ W0,
    const float* __restrict__ b0v, void* __restrict__ O0, float scl0,
    const bf16* __restrict__ A1, const bf16* __restrict__ W1,
    const float* __restrict__ b1v, void* __restrict__ O1, float scl1)
{
    __shared__ bf16 ldsA[128 * 64];
    __shared__ bf16 ldsW[128 * 64];

    const bf16* A     = blockIdx.z ? A1 : A0;
    const bf16* W     = blockIdx.z ? W1 : W0;
    const float* bias = blockIdx.z ? b1v : b0v;
    void* Out         = blockIdx.z ? O1 : O0;
    const float scl   = blockIdx.z ? scl1 : scl0;

    const int tid  = threadIdx.x;
    const int wave = tid >> 6, lane = tid & 63;
    const int quad = lane >> 4, l15 = lane & 15;
    const int wr = wave >> 1, wc = wave & 1;
    const int m0 = blockIdx.y * 128, n0 = blockIdx.x * 128;

    floatx4 acc[4][4];
#pragma unroll
    for (int i = 0; i < 4; ++i)
#pragma unroll
        for (int j = 0; j < 4; ++j) acc[i][j] = fzero4();

    const int ro = lane >> 3;
    const int gc = (lane & 7) ^ ro;
    const bf16* gA = A + (size_t)(m0 + wave * 32 + ro) * 1024 + gc * 8;
    const bf16* gW = W + (size_t)(n0 + wave * 32 + ro) * 1024 + gc * 8;

    for (int kt = 0; kt < 16; ++kt) {
        __syncthreads();
#pragma unroll
        for (int j = 0; j < 4; ++j)
            async_ld16((const void*)(gA + kt * 64 + j * 8 * 1024), &ldsA[(wave * 32 + j * 8) * 64]);
#pragma unroll
        for (int j = 0; j < 4; ++j)
            async_ld16((const void*)(gW + kt * 64 + j * 8 * 1024), &ldsW[(wave * 32 + j * 8) * 64]);
        __syncthreads();

#pragma unroll
        for (int ks = 0; ks < 2; ++ks) {
            const int pos = ((ks * 4 + quad) ^ (l15 & 7)) * 8;
            bf16x8 af[4], bw[4];
#pragma unroll
            for (int i = 0; i < 4; ++i)
                af[i] = *(const bf16x8*)(&ldsA[(wr * 64 + i * 16 + l15) * 64 + pos]);
#pragma unroll
            for (int j = 0; j < 4; ++j)
                bw[j] = *(const bf16x8*)(&ldsW[(wc * 64 + j * 16 + l15) * 64 + pos]);
#pragma unroll
            for (int i = 0; i < 4; ++i)
#pragma unroll
                for (int j = 0; j < 4; ++j)
                    acc[i][j] = __builtin_amdgcn_mfma_f32_16x16x32_bf16(af[i], bw[j], acc[i][j], 0, 0, 0);
        }
    }

#pragma unroll
    for (int i = 0; i < 4; ++i) {
#pragma unroll
        for (int j = 0; j < 4; ++j) {
#pragma unroll
            for (int r = 0; r < 4; ++r) {
                int m = m0 + wr * 64 + i * 16 + quad * 4 + r;
                int n = n0 + wc * 64 + j * 16 + l15;
                float val = (acc[i][j][r] + bias[n]) * scl;
                if (OMODE == 2) {
                    ((float*)Out)[(size_t)m * 1024 + n] = val;
                } else {
                    int b = m >> 11, t = m & 2047;
                    int h = n >> 6,  d = n & 63;
                    size_t addr;
                    if (OMODE == 0)
                        addr = ((size_t)(b * N_HEAD + h) * T_SEQ + t) * HD + d;
                    else
                        addr = ((size_t)(b * N_HEAD + h) * HD + d) * T_SEQ + t;
                    ((bf16*)Out)[addr] = (bf16)val;
                }
            }
        }
    }
}

// Flash-style causal attention, S^T formulation, 256-row q-supertiles.
// Qh (pre-scaled by 1/8*log2e), Kh: [B,H,T,64] bf16.  Vt: [B,H,64,T] bf16.  AO: [B,T,D] bf16.
// grid (4, 64), block 512 (8 waves x 32 q-rows = 256 q-rows/block).
// Each block processes supertile pair {7-pair, pair}: exactly 18 K-iterations -> perfect balance.
// LDS 68 KB -> 2 blocks/CU (16 waves/CU).
__global__ __launch_bounds__(512, 4) void attn_kernel(
    const bf16* __restrict__ Qh, const bf16* __restrict__ Kh,
    const bf16* __restrict__ Vt, bf16* __restrict__ AO)
{
    __shared__ bf16 Ks[128 * 64];   // 16 KB, XOR-swizzled chunks (slot c holds chunk c^(r&7))
    __shared__ bf16 Vts[64 * 128];  // 16 KB, XOR-swizzled (slot c holds chunk c^(d&15))
    __shared__ bf16 Ps[256 * 72];   // 36 KB, wave-private rows

    const int tid  = threadIdx.x;
    const int wave = tid >> 6, lane = tid & 63;
    const int quad = lane >> 4, l15 = lane & 15;
    const int pair = blockIdx.x, bh = blockIdx.y;
    const size_t base = (size_t)bh * T_SEQ * HD;
    const int bb = bh >> 4, hh = bh & 15;

    // K staging: wave stages rows [wave*16, wave*16+16); lane -> row +j*8+(lane>>3)
    const int kro = lane >> 3;
    const int kgc = (lane & 7) ^ kro;

    for (int phase = 0; phase < 2; ++phase) {
        const int st = phase ? pair : 7 - pair;
        const int ktmax = 2 * st + 1;
        const int qb = st * 256 + wave * 32;   // this wave's global q base

        // Q fragments (pre-scaled), B-operand layout: l15 = q, k = quad*8+j
        bf16x8 qf[2][2];
        const bf16* qbase = Qh + base + (size_t)qb * HD;
#pragma unroll
        for (int ti = 0; ti < 2; ++ti)
#pragma unroll
            for (int ks = 0; ks < 2; ++ks)
                qf[ti][ks] = *(const bf16x8*)(qbase + (ti * 16 + l15) * HD + ks * 32 + quad * 8);

        float mrow[2] = {-1e30f, -1e30f}, lrow[2] = {0.f, 0.f};
        floatx4 oacc[2][4];
#pragma unroll
        for (int ti = 0; ti < 2; ++ti)
#pragma unroll
            for (int nj = 0; nj < 4; ++nj) oacc[ti][nj] = fzero4();

        for (int kt = 0; kt <= ktmax; ++kt) {
            __syncthreads();   // all waves done reading Ks/Vts from prev iter
#pragma unroll
            for (int j = 0; j < 2; ++j)
                async_ld16((const void*)(Kh + base +
                               (size_t)(kt * 128 + wave * 16 + j * 8 + kro) * HD + kgc * 8),
                           &Ks[(wave * 16 + j * 8) * 64]);
#pragma unroll
            for (int j = 0; j < 2; ++j) {
                int d = wave * 8 + j * 4 + (lane >> 4);
                int gcv = (lane & 15) ^ (d & 15);
                async_ld16((const void*)(Vt + base + (size_t)d * T_SEQ + kt * 128 + gcv * 8),
                           &Vts[(wave * 8 + j * 4) * 128]);
            }
            __syncthreads();   // staging visible

            const int limr = qb + 31 - kt * 128;
            if (limr < 0) continue;            // no work for this wave (barriers already done)
            const int gksmax = limr >= 96 ? 3 : (limr >> 5);
            const int lim = 2 * gksmax + 1;    // tj limit (odd-rounded so PV reads are covered)
            const bool msk = (qb < kt * 128 + 127);

            // S^T = K Q^T : A = K-frag (l15 = k-row), B = Q-frag (l15 = q)
            floatx4 sacc[2][8];
#pragma unroll
            for (int ti = 0; ti < 2; ++ti)
#pragma unroll
                for (int tj = 0; tj < 8; ++tj) sacc[ti][tj] = fzero4();
#pragma unroll
            for (int ks = 0; ks < 2; ++ks) {
                const int pos = ((ks * 4 + quad) ^ (l15 & 7)) * 8;
#pragma unroll
                for (int tj = 0; tj < 8; ++tj) {
                    if (tj <= lim) {
                        bf16x8 kf = *(const bf16x8*)(&Ks[(tj * 16 + l15) * 64 + pos]);
                        sacc[0][tj] = __builtin_amdgcn_mfma_f32_16x16x32_bf16(kf, qf[0][ks], sacc[0][tj], 0, 0, 0);
                        sacc[1][tj] = __builtin_amdgcn_mfma_f32_16x16x32_bf16(kf, qf[1][ks], sacc[1][tj], 0, 0, 0);
                    }
                }
            }

            // online softmax (scores already scaled): lane owns q = qb+ti*16+l15
#pragma unroll
            for (int ti = 0; ti < 2; ++ti) {
                const int qg = qb + ti * 16 + l15;
                float mx = -1e30f;
#pragma unroll
                for (int tj = 0; tj < 8; ++tj) {
                    if (tj <= lim) {
#pragma unroll
                        for (int r = 0; r < 4; ++r) {
                            float s = sacc[ti][tj][r];
                            if (msk && (kt * 128 + tj * 16 + quad * 4 + r) > qg) s = -1e30f;
                            sacc[ti][tj][r] = s;
                            mx = fmaxf(mx, s);
                        }
                    }
                }
                mx = fmaxf(mx, __shfl_xor(mx, 16));
                mx = fmaxf(mx, __shfl_xor(mx, 32));
                float mnew  = fmaxf(mrow[ti], mx);
                float alpha = exp2f(mrow[ti] - mnew);
                float rsum  = 0.f;
#pragma unroll
                for (int tj = 0; tj < 8; ++tj) {
                    if (tj <= lim) {
#pragma unroll
                        for (int r = 0; r < 4; ++r) {
                            float p = exp2f(sacc[ti][tj][r] - mnew);
                            rsum += p;
                            sacc[ti][tj][r] = p;
                        }
                    }
                }
                rsum += __shfl_xor(rsum, 16);
                rsum += __shfl_xor(rsum, 32);
                lrow[ti] = lrow[ti] * alpha + rsum;
                mrow[ti] = mnew;
#pragma unroll
                for (int r = 0; r < 4; ++r) {
                    float ar = __shfl(alpha, quad * 4 + r);
#pragma unroll
                    for (int nj = 0; nj < 4; ++nj)
                        oacc[ti][nj][r] *= ar;
                }
            }

            // P -> LDS and O += P V, in two k-halves (Ps wave-private rows)
#pragma unroll
            for (int h2 = 0; h2 < 2; ++h2) {
                if (4 * h2 > lim) break;
#pragma unroll
                for (int ti = 0; ti < 2; ++ti) {
                    const int ql = wave * 32 + ti * 16 + l15;
#pragma unroll
                    for (int tjo = 0; tjo < 4; ++tjo) {
                        int tj = 4 * h2 + tjo;
                        if (tj <= lim) {
                            bf16x4 pv;
#pragma unroll
                            for (int r = 0; r < 4; ++r) pv[r] = (bf16)sacc[ti][tj][r];
                            *(bf16x4*)(&Ps[ql * 72 + tjo * 16 + quad * 4]) = pv;
                        }
                    }
                }
#pragma unroll
                for (int ks2 = 0; ks2 < 2; ++ks2) {
                    const int gks = 2 * h2 + ks2;
                    if (gks > gksmax) break;
                    bf16x8 pf[2];
                    pf[0] = *(const bf16x8*)(&Ps[(wave * 32 + l15) * 72 + ks2 * 32 + quad * 8]);
                    pf[1] = *(const bf16x8*)(&Ps[(wave * 32 + 16 + l15) * 72 + ks2 * 32 + quad * 8]);
#pragma unroll
                    for (int nj = 0; nj < 4; ++nj) {
                        int pos = ((gks * 4 + quad) ^ l15) * 8;
                        bf16x8 vf = *(const bf16x8*)(&Vts[(nj * 16 + l15) * 128 + pos]);
                        oacc[0][nj] = __builtin_amdgcn_mfma_f32_16x16x32_bf16(pf[0], vf, oacc[0][nj], 0, 0, 0);
                        oacc[1][nj] = __builtin_amdgcn_mfma_f32_16x16x32_bf16(pf[1], vf, oacc[1][nj], 0, 0, 0);
                    }
                }
            }
        }

        // epilogue for this supertile: O /= l ; rows = quad*4+r, cols d = nj*16+l15
#pragma unroll
        for (int ti = 0; ti < 2; ++ti) {
#pragma unroll
            for (int r = 0; r < 4; ++r) {
                float lv = __shfl(lrow[ti], quad * 4 + r);
                float rl = 1.f / lv;
                int qrow = qb + ti * 16 + quad * 4 + r;
#pragma unroll
                for (int nj = 0; nj < 4; ++nj) {
                    int d = nj * 16 + l15;
                    AO[((size_t)(bb * T_SEQ + qrow)) * D_MODEL + hh * HD + d] =
                        (bf16)(oacc[ti][nj][r] * rl);
                }
            }
        }
    }
}

extern "C" void kernel_launch(void* const* d_in, const int* in_sizes, int n_in,
                              void* d_out, int out_size, void* d_ws, size_t ws_size,
                              hipStream_t stream)
{
    const float* q  = (const float*)d_in[0];
    const float* k  = (const float*)d_in[1];
    const float* v  = (const float*)d_in[2];
    const float* wq = (const float*)d_in[3];
    const float* bq = (const float*)d_in[4];
    const float* wk = (const float*)d_in[5];
    const float* bk = (const float*)d_in[6];
    const float* wv = (const float*)d_in[7];
    const float* bv = (const float*)d_in[8];
    const float* wo = (const float*)d_in[9];
    const float* bo = (const float*)d_in[10];

    char* ws  = (char*)d_ws;
    char* dob = (char*)d_out;
    const size_t MB = 1024 * 1024;

    // ws (<=56 MB used): Wqb[0,2) Wkb[2,4) Wvb[4,6) Vb[6,22) Qh[22,38) Kh[38,54) Wob[54,56)
    // AO reuses Vb's region [6,22) after the V-GEMM consumed Vb.
    // d_out (32 MB): Qb[0,16) Kb[16,32) -> after QK-GEMM: Vt[0,16) -> final fp32 out.
    bf16* Wqb = (bf16*)(ws);
    bf16* Wkb = (bf16*)(ws + 2 * MB);
    bf16* Wvb = (bf16*)(ws + 4 * MB);
    bf16* Vb  = (bf16*)(ws + 6 * MB);
    bf16* AO  = (bf16*)(ws + 6 * MB);
    bf16* Qh  = (bf16*)(ws + 22 * MB);
    bf16* Kh  = (bf16*)(ws + 38 * MB);
    bf16* Wob = (bf16*)(ws + 54 * MB);
    bf16* Qb  = (bf16*)(dob);
    bf16* Kb  = (bf16*)(dob + 16 * MB);
    bf16* Vt  = (bf16*)(dob);

    const int NQ8 = M_ROWS * D_MODEL / 8;   // 1M
    const int NW8 = D_MODEL * D_MODEL / 8;  // 128K
    const float QSCALE = 0.18033688011112042f;  // (1/sqrt(64)) * log2(e)

    CvtArgs ca;
    ca.s[0] = q;  ca.d[0] = Qb;  ca.n[0] = NQ8;
    ca.s[1] = k;  ca.d[1] = Kb;  ca.n[1] = NQ8;
    ca.s[2] = v;  ca.d[2] = Vb;  ca.n[2] = NQ8;
    ca.s[3] = wq; ca.d[3] = Wqb; ca.n[3] = NW8;
    ca.s[4] = wk; ca.d[4] = Wkb; ca.n[4] = NW8;
    ca.s[5] = wv; ca.d[5] = Wvb; ca.n[5] = NW8;
    ca.s[6] = wo; ca.d[6] = Wob; ca.n[6] = NW8;

    hipLaunchKernelGGL(cvt7_kernel, dim3(512, 7), dim3(256), 0, stream, ca);
    hipLaunchKernelGGL((gemm_bf16<0>), dim3(8, 64, 2), dim3(256), 0, stream,
                       Qb, Wqb, bq, (void*)Qh, QSCALE,
                       Kb, Wkb, bk, (void*)Kh, 1.0f);
    hipLaunchKernelGGL((gemm_bf16<1>), dim3(8, 64, 1), dim3(256), 0, stream,
                       Vb, Wvb, bv, (void*)Vt, 1.0f,
                       Vb, Wvb, bv, (void*)Vt, 1.0f);
    hipLaunchKernelGGL(attn_kernel, dim3(4, 64), dim3(512), 0, stream, Qh, Kh, Vt, AO);
    hipLaunchKernelGGL((gemm_bf16<2>), dim3(8, 64, 1), dim3(256), 0, stream,
                       AO, Wob, bo, d_out, 1.0f,
                       AO, Wob, bo, d_out, 1.0f);
}

// Round 6
// 381.982 us; speedup vs baseline: 1.5773x; 1.5773x over previous
//
#include <hip/hip_runtime.h>
#include <hip/hip_bf16.h>

#define D_MODEL 1024
#define N_HEAD  16
#define HD      64
#define T_SEQ   2048
#define B_SZ    4
#define M_ROWS  (B_SZ * T_SEQ)   // 8192

typedef __bf16 bf16;
typedef __bf16 bf16x4 __attribute__((ext_vector_type(4)));
typedef __bf16 bf16x8 __attribute__((ext_vector_type(8)));
typedef float  floatx4 __attribute__((ext_vector_type(4)));

__device__ __forceinline__ floatx4 fzero4() {
    floatx4 z = {0.f, 0.f, 0.f, 0.f};
    return z;
}

// async global->LDS, 16B/lane. LDS dest = wave-uniform base + lane*16.
__device__ __forceinline__ void async_ld16(const void* g, void* l) {
    __builtin_amdgcn_global_load_lds(
        (const __attribute__((address_space(1))) void*)g,
        (__attribute__((address_space(3))) void*)l,
        16, 0, 0);
}

struct CvtArgs {
    const float* s[7];
    bf16* d[7];
    int n[7];
};

// fused fp32 -> bf16 convert: 7 segments selected by blockIdx.y
__global__ __launch_bounds__(256) void cvt7_kernel(CvtArgs a)
{
    const float* src = a.s[blockIdx.y];
    bf16* dst = a.d[blockIdx.y];
    int n8 = a.n[blockIdx.y];
    int i = blockIdx.x * blockDim.x + threadIdx.x;
    int stride = gridDim.x * blockDim.x;
    for (; i < n8; i += stride) {
        float4 x = ((const float4*)src)[2 * i];
        float4 y = ((const float4*)src)[2 * i + 1];
        bf16x8 o;
        o[0] = (bf16)x.x; o[1] = (bf16)x.y; o[2] = (bf16)x.z; o[3] = (bf16)x.w;
        o[4] = (bf16)y.x; o[5] = (bf16)y.y; o[6] = (bf16)y.z; o[7] = (bf16)y.w;
        ((bf16x8*)dst)[i] = o;
    }
}

// C[8192,1024] = (A(bf16) @ W^T(bf16 [N,K]) + bias) * scl.
// LDS tiles XOR-swizzled: row r's 16B chunk c stored at pos c^(r&7).
// OMODE: 0 = bf16 head-split [B,H,T,64]; 1 = bf16 [B,H,64,T] (V); 2 = fp32 [M,N]
template <int OMODE>
__global__ __launch_bounds__(256) void gemm_bf16(
    const bf16* __restrict__ A0, const bf16* __restrict__ W0,
    const float* __restrict__ b0v, void* __restrict__ O0, float scl0,
    const bf16* __restrict__ A1, const bf16* __restrict__ W1,
    const float* __restrict__ b1v, void* __restrict__ O1, float scl1)
{
    __shared__ bf16 ldsA[128 * 64];
    __shared__ bf16 ldsW[128 * 64];

    const bf16* A     = blockIdx.z ? A1 : A0;
    const bf16* W     = blockIdx.z ? W1 : W0;
    const float* bias = blockIdx.z ? b1v : b0v;
    void* Out         = blockIdx.z ? O1 : O0;
    const float scl   = blockIdx.z ? scl1 : scl0;

    const int tid  = threadIdx.x;
    const int wave = tid >> 6, lane = tid & 63;
    const int quad = lane >> 4, l15 = lane & 15;
    const int wr = wave >> 1, wc = wave & 1;
    const int m0 = blockIdx.y * 128, n0 = blockIdx.x * 128;

    floatx4 acc[4][4];
#pragma unroll
    for (int i = 0; i < 4; ++i)
#pragma unroll
        for (int j = 0; j < 4; ++j) acc[i][j] = fzero4();

    const int ro = lane >> 3;
    const int gc = (lane & 7) ^ ro;
    const bf16* gA = A + (size_t)(m0 + wave * 32 + ro) * 1024 + gc * 8;
    const bf16* gW = W + (size_t)(n0 + wave * 32 + ro) * 1024 + gc * 8;

    for (int kt = 0; kt < 16; ++kt) {
        __syncthreads();
#pragma unroll
        for (int j = 0; j < 4; ++j)
            async_ld16((const void*)(gA + kt * 64 + j * 8 * 1024), &ldsA[(wave * 32 + j * 8) * 64]);
#pragma unroll
        for (int j = 0; j < 4; ++j)
            async_ld16((const void*)(gW + kt * 64 + j * 8 * 1024), &ldsW[(wave * 32 + j * 8) * 64]);
        __syncthreads();

#pragma unroll
        for (int ks = 0; ks < 2; ++ks) {
            const int pos = ((ks * 4 + quad) ^ (l15 & 7)) * 8;
            bf16x8 af[4], bw[4];
#pragma unroll
            for (int i = 0; i < 4; ++i)
                af[i] = *(const bf16x8*)(&ldsA[(wr * 64 + i * 16 + l15) * 64 + pos]);
#pragma unroll
            for (int j = 0; j < 4; ++j)
                bw[j] = *(const bf16x8*)(&ldsW[(wc * 64 + j * 16 + l15) * 64 + pos]);
#pragma unroll
            for (int i = 0; i < 4; ++i)
#pragma unroll
                for (int j = 0; j < 4; ++j)
                    acc[i][j] = __builtin_amdgcn_mfma_f32_16x16x32_bf16(af[i], bw[j], acc[i][j], 0, 0, 0);
        }
    }

#pragma unroll
    for (int i = 0; i < 4; ++i) {
#pragma unroll
        for (int j = 0; j < 4; ++j) {
#pragma unroll
            for (int r = 0; r < 4; ++r) {
                int m = m0 + wr * 64 + i * 16 + quad * 4 + r;
                int n = n0 + wc * 64 + j * 16 + l15;
                float val = (acc[i][j][r] + bias[n]) * scl;
                if (OMODE == 2) {
                    ((float*)Out)[(size_t)m * 1024 + n] = val;
                } else {
                    int b = m >> 11, t = m & 2047;
                    int h = n >> 6,  d = n & 63;
                    size_t addr;
                    if (OMODE == 0)
                        addr = ((size_t)(b * N_HEAD + h) * T_SEQ + t) * HD + d;
                    else
                        addr = ((size_t)(b * N_HEAD + h) * HD + d) * T_SEQ + t;
                    ((bf16*)Out)[addr] = (bf16)val;
                }
            }
        }
    }
}

// Flash-style causal attention, S^T formulation, paired q-tiles for perfect balance.
// Qh (pre-scaled by 1/8*log2e), Kh: [B,H,T,64] bf16.  Vt: [B,H,64,T] bf16.  AO: [B,T,D] bf16.
// grid (8, 64), block 256 (4 waves x 32 q-rows). Block bx processes q-tiles
// {15-bx, bx} sequentially -> exactly 17 K-iterations per block, 512 blocks,
// all co-resident (3 blocks/CU at 50 KB LDS). No straggler tail.
__global__ __launch_bounds__(256, 3) void attn_kernel(
    const bf16* __restrict__ Qh, const bf16* __restrict__ Kh,
    const bf16* __restrict__ Vt, bf16* __restrict__ AO)
{
    __shared__ bf16 Ks[128 * 64];   // 16 KB, XOR-swizzled chunks (slot c holds chunk c^(r&7))
    __shared__ bf16 Vts[64 * 128];  // 16 KB, XOR-swizzled (slot c holds chunk c^(d&15))
    __shared__ bf16 Ps[128 * 72];   // 18 KB, half-k P buffer (2-pass), wave-private rows

    const int tid  = threadIdx.x;
    const int wave = tid >> 6, lane = tid & 63;
    const int quad = lane >> 4, l15 = lane & 15;
    const int bh = blockIdx.y;
    const size_t base = (size_t)bh * T_SEQ * HD;
    const int bb = bh >> 4, hh = bh & 15;

    // staging lane->addr precompute
    const int kro = lane >> 3;
    const int kgc = (lane & 7) ^ kro;
    const bf16* kgbase = Kh + base + (size_t)(wave * 32 + kro) * HD + kgc * 8;
    const int vrow_lo = (lane >> 4);
    const int vchunk  = (lane & 15);

    for (int phase = 0; phase < 2; ++phase) {
        const int qt = phase ? blockIdx.x : 15 - blockIdx.x;

        // Q fragments (pre-scaled), B-operand layout: lane l15 = q, k = quad*8+j
        bf16x8 qf[2][2];
        const bf16* qbase = Qh + base + (size_t)(qt * 128 + wave * 32) * HD;
#pragma unroll
        for (int ti = 0; ti < 2; ++ti)
#pragma unroll
            for (int ks = 0; ks < 2; ++ks)
                qf[ti][ks] = *(const bf16x8*)(qbase + (ti * 16 + l15) * HD + ks * 32 + quad * 8);

        float mrow[2] = {-1e30f, -1e30f}, lrow[2] = {0.f, 0.f};
        floatx4 oacc[2][4];
#pragma unroll
        for (int ti = 0; ti < 2; ++ti)
#pragma unroll
            for (int nj = 0; nj < 4; ++nj) oacc[ti][nj] = fzero4();

        for (int kt = 0; kt <= qt; ++kt) {
            __syncthreads();   // all waves done reading Ks/Vts from prev iter
#pragma unroll
            for (int j = 0; j < 4; ++j)
                async_ld16((const void*)(kgbase + (size_t)(kt * 128 + j * 8) * HD),
                           &Ks[(wave * 32 + j * 8) * 64]);
#pragma unroll
            for (int j = 0; j < 4; ++j) {
                int d = wave * 16 + j * 4 + vrow_lo;
                int gcv = vchunk ^ (d & 15);
                async_ld16((const void*)(Vt + base + (size_t)d * T_SEQ + kt * 128 + gcv * 8),
                           &Vts[(wave * 16 + j * 4) * 128]);
            }
            __syncthreads();   // staging visible

            const bool diag = (kt == qt);
            const int lim = diag ? (2 * wave + 1) : 7;   // max tj with any unmasked k

            // S^T = K Q^T : A = K-frag (l15 = k-row), B = Q-frag (l15 = q)
            floatx4 sacc[2][8];
#pragma unroll
            for (int ti = 0; ti < 2; ++ti)
#pragma unroll
                for (int tj = 0; tj < 8; ++tj) sacc[ti][tj] = fzero4();
#pragma unroll
            for (int ks = 0; ks < 2; ++ks) {
                const int pos = ((ks * 4 + quad) ^ (l15 & 7)) * 8;
#pragma unroll
                for (int tj = 0; tj < 8; ++tj) {
                    if (tj <= lim) {
                        bf16x8 kf = *(const bf16x8*)(&Ks[(tj * 16 + l15) * 64 + pos]);
                        sacc[0][tj] = __builtin_amdgcn_mfma_f32_16x16x32_bf16(kf, qf[0][ks], sacc[0][tj], 0, 0, 0);
                        sacc[1][tj] = __builtin_amdgcn_mfma_f32_16x16x32_bf16(kf, qf[1][ks], sacc[1][tj], 0, 0, 0);
                    }
                }
            }

            // online softmax (scores pre-scaled): lane owns q = l15 (per ti)
#pragma unroll
            for (int ti = 0; ti < 2; ++ti) {
                const int ql = wave * 32 + ti * 16 + l15;
                float mx = -1e30f;
#pragma unroll
                for (int tj = 0; tj < 8; ++tj) {
                    if (tj <= lim) {
#pragma unroll
                        for (int r = 0; r < 4; ++r) {
                            float s = sacc[ti][tj][r];
                            if (diag && (tj * 16 + quad * 4 + r) > ql) s = -1e30f;
                            sacc[ti][tj][r] = s;
                            mx = fmaxf(mx, s);
                        }
                    }
                }
                mx = fmaxf(mx, __shfl_xor(mx, 16));
                mx = fmaxf(mx, __shfl_xor(mx, 32));
                float mnew  = fmaxf(mrow[ti], mx);
                float alpha = exp2f(mrow[ti] - mnew);
                float rsum  = 0.f;
#pragma unroll
                for (int tj = 0; tj < 8; ++tj) {
                    if (tj <= lim) {
#pragma unroll
                        for (int r = 0; r < 4; ++r) {
                            float p = exp2f(sacc[ti][tj][r] - mnew);
                            rsum += p;
                            sacc[ti][tj][r] = p;
                        }
                    }
                }
                rsum += __shfl_xor(rsum, 16);
                rsum += __shfl_xor(rsum, 32);
                lrow[ti] = lrow[ti] * alpha + rsum;
                mrow[ti] = mnew;
#pragma unroll
                for (int r = 0; r < 4; ++r) {
                    float ar = __shfl(alpha, quad * 4 + r);
#pragma unroll
                    for (int nj = 0; nj < 4; ++nj)
                        oacc[ti][nj][r] *= ar;
                }
            }

            // P -> LDS and O += P V, in two k-halves (Ps wave-private rows)
#pragma unroll
            for (int h2 = 0; h2 < 2; ++h2) {
                if (4 * h2 > lim) break;
#pragma unroll
                for (int ti = 0; ti < 2; ++ti) {
                    const int ql = wave * 32 + ti * 16 + l15;
#pragma unroll
                    for (int tjo = 0; tjo < 4; ++tjo) {
                        int tj = 4 * h2 + tjo;
                        if (tj <= lim) {
                            bf16x4 pv;
#pragma unroll
                            for (int r = 0; r < 4; ++r) pv[r] = (bf16)sacc[ti][tj][r];
                            *(bf16x4*)(&Ps[ql * 72 + tjo * 16 + quad * 4]) = pv;
                        }
                    }
                }
#pragma unroll
                for (int ks2 = 0; ks2 < 2; ++ks2) {
                    const int gks = 2 * h2 + ks2;
                    if (diag && gks > wave) break;
                    bf16x8 pf[2];
                    pf[0] = *(const bf16x8*)(&Ps[(wave * 32 + l15) * 72 + ks2 * 32 + quad * 8]);
                    pf[1] = *(const bf16x8*)(&Ps[(wave * 32 + 16 + l15) * 72 + ks2 * 32 + quad * 8]);
#pragma unroll
                    for (int nj = 0; nj < 4; ++nj) {
                        int pos = ((gks * 4 + quad) ^ l15) * 8;
                        bf16x8 vf = *(const bf16x8*)(&Vts[(nj * 16 + l15) * 128 + pos]);
                        oacc[0][nj] = __builtin_amdgcn_mfma_f32_16x16x32_bf16(pf[0], vf, oacc[0][nj], 0, 0, 0);
                        oacc[1][nj] = __builtin_amdgcn_mfma_f32_16x16x32_bf16(pf[1], vf, oacc[1][nj], 0, 0, 0);
                    }
                }
            }
        }

        // epilogue: O /= l ; O rows = quad*4+r, cols d = nj*16+l15
#pragma unroll
        for (int ti = 0; ti < 2; ++ti) {
#pragma unroll
            for (int r = 0; r < 4; ++r) {
                float lv = __shfl(lrow[ti], quad * 4 + r);
                float rl = 1.f / lv;
                int qrow = qt * 128 + wave * 32 + ti * 16 + quad * 4 + r;
#pragma unroll
                for (int nj = 0; nj < 4; ++nj) {
                    int d = nj * 16 + l15;
                    AO[((size_t)(bb * T_SEQ + qrow)) * D_MODEL + hh * HD + d] =
                        (bf16)(oacc[ti][nj][r] * rl);
                }
            }
        }
    }
}

extern "C" void kernel_launch(void* const* d_in, const int* in_sizes, int n_in,
                              void* d_out, int out_size, void* d_ws, size_t ws_size,
                              hipStream_t stream)
{
    const float* q  = (const float*)d_in[0];
    const float* k  = (const float*)d_in[1];
    const float* v  = (const float*)d_in[2];
    const float* wq = (const float*)d_in[3];
    const float* bq = (const float*)d_in[4];
    const float* wk = (const float*)d_in[5];
    const float* bk = (const float*)d_in[6];
    const float* wv = (const float*)d_in[7];
    const float* bv = (const float*)d_in[8];
    const float* wo = (const float*)d_in[9];
    const float* bo = (const float*)d_in[10];

    char* ws  = (char*)d_ws;
    char* dob = (char*)d_out;
    const size_t MB = 1024 * 1024;

    // ws (<=56 MB): Wqb[0,2) Wkb[2,4) Wvb[4,6) Vb[6,22) Qh[22,38) Kh[38,54) Wob[54,56)
    // AO reuses Vb's region [6,22) after the V-GEMM consumed Vb.
    // d_out (32 MB): Qb[0,16) Kb[16,32) -> after QK-GEMM: Vt[0,16) -> final fp32 out.
    bf16* Wqb = (bf16*)(ws);
    bf16* Wkb = (bf16*)(ws + 2 * MB);
    bf16* Wvb = (bf16*)(ws + 4 * MB);
    bf16* Vb  = (bf16*)(ws + 6 * MB);
    bf16* AO  = (bf16*)(ws + 6 * MB);
    bf16* Qh  = (bf16*)(ws + 22 * MB);
    bf16* Kh  = (bf16*)(ws + 38 * MB);
    bf16* Wob = (bf16*)(ws + 54 * MB);
    bf16* Qb  = (bf16*)(dob);
    bf16* Kb  = (bf16*)(dob + 16 * MB);
    bf16* Vt  = (bf16*)(dob);

    const int NQ8 = M_ROWS * D_MODEL / 8;   // 1M
    const int NW8 = D_MODEL * D_MODEL / 8;  // 128K
    const float QSCALE = 0.18033688011112042f;  // (1/sqrt(64)) * log2(e)

    CvtArgs ca;
    ca.s[0] = q;  ca.d[0] = Qb;  ca.n[0] = NQ8;
    ca.s[1] = k;  ca.d[1] = Kb;  ca.n[1] = NQ8;
    ca.s[2] = v;  ca.d[2] = Vb;  ca.n[2] = NQ8;
    ca.s[3] = wq; ca.d[3] = Wqb; ca.n[3] = NW8;
    ca.s[4] = wk; ca.d[4] = Wkb; ca.n[4] = NW8;
    ca.s[5] = wv; ca.d[5] = Wvb; ca.n[5] = NW8;
    ca.s[6] = wo; ca.d[6] = Wob; ca.n[6] = NW8;

    hipLaunchKernelGGL(cvt7_kernel, dim3(512, 7), dim3(256), 0, stream, ca);
    hipLaunchKernelGGL((gemm_bf16<0>), dim3(8, 64, 2), dim3(256), 0, stream,
                       Qb, Wqb, bq, (void*)Qh, QSCALE,
                       Kb, Wkb, bk, (void*)Kh, 1.0f);
    hipLaunchKernelGGL((gemm_bf16<1>), dim3(8, 64, 1), dim3(256), 0, stream,
                       Vb, Wvb, bv, (void*)Vt, 1.0f,
                       Vb, Wvb, bv, (void*)Vt, 1.0f);
    hipLaunchKernelGGL(attn_kernel, dim3(8, 64), dim3(256), 0, stream, Qh, Kh, Vt, AO);
    hipLaunchKernelGGL((gemm_bf16<2>), dim3(8, 64, 1), dim3(256), 0, stream,
                       AO, Wob, bo, d_out, 1.0f,
                       AO, Wob, bo, d_out, 1.0f);
}